// Round 1
// baseline (309.994 us; speedup 1.0000x reference)
//
#include <hip/hip_runtime.h>
#include <hip/hip_bf16.h>
#include <math.h>

#define NNODES 8192
#define NEDGES 262144
#define INDIM  512
#define H1     256
#define H2     64

// ---------------- degree / norm / CSR build ----------------

__global__ void deg_kernel(const int* __restrict__ src, const int* __restrict__ dst,
                           int* deg_out, int* deg_in) {
    int e = blockIdx.x * blockDim.x + threadIdx.x;
    if (e < NEDGES) {
        atomicAdd(&deg_out[src[e]], 1);
        atomicAdd(&deg_in[dst[e]], 1);
    }
}

__global__ void norm_kernel(const int* __restrict__ deg_out, const int* __restrict__ deg_in,
                            float* norm_out, float* norm_in) {
    int i = blockIdx.x * blockDim.x + threadIdx.x;
    if (i < NNODES) {
        norm_out[i] = 1.0f / sqrtf(fmaxf((float)deg_out[i], 1.0f));
        norm_in[i]  = 1.0f / sqrtf(fmaxf((float)deg_in[i],  1.0f));
    }
}

// exclusive prefix sum of deg_in over 8192 nodes, single block of 1024 threads
__global__ __launch_bounds__(1024) void scan_kernel(const int* __restrict__ deg_in,
                                                    int* __restrict__ row_start) {
    __shared__ int part[1024];
    int t = threadIdx.x;
    int v[8]; int s = 0;
#pragma unroll
    for (int u = 0; u < 8; u++) { v[u] = deg_in[t * 8 + u]; s += v[u]; }
    part[t] = s; __syncthreads();
    for (int off = 1; off < 1024; off <<= 1) {
        int x = part[t];
        if (t >= off) x += part[t - off];
        __syncthreads();
        part[t] = x;
        __syncthreads();
    }
    int run = part[t] - s;   // exclusive prefix of this thread's chunk
#pragma unroll
    for (int u = 0; u < 8; u++) { row_start[t * 8 + u] = run; run += v[u]; }
    if (t == 1023) row_start[NNODES] = run;
}

__global__ void bucket_kernel(const int* __restrict__ src, const int* __restrict__ dst,
                              const int* __restrict__ row_start,
                              int* cursor, int* __restrict__ sorted_src) {
    int e = blockIdx.x * blockDim.x + threadIdx.x;
    if (e < NEDGES) {
        int d = dst[e];
        int p = atomicAdd(&cursor[d], 1);
        sorted_src[row_start[d] + p] = src[e];
    }
}

// ---------------- fp32 tiled GEMM: out[i][c] = (X@W)[i][c] * scale[i] ----------------
// BM=BN=64, BK=16, 256 threads, 4x4 microtile per thread.

template<int K, int NC>
__global__ __launch_bounds__(256) void gemm_scale_kernel(const float* __restrict__ X,
                                                         const float* __restrict__ W,
                                                         const float* __restrict__ scale,
                                                         float* __restrict__ out) {
    __shared__ float As[16][68];   // [k][row], padded for b128-aligned, low-conflict reads
    __shared__ float Bs[16][68];   // [k][col]
    const int tx = threadIdx.x, ty = threadIdx.y;
    const int tid = ty * 16 + tx;
    const int i0 = blockIdx.x * 64;
    const int j0 = blockIdx.y * 64;
    float acc[4][4] = {};

    for (int k0 = 0; k0 < K; k0 += 16) {
        // A tile 64x16 (row-major in global, store transposed [k][row])
        {
            int r = tid >> 2, kq = (tid & 3) * 4;
            float4 va = *(const float4*)&X[(size_t)(i0 + r) * K + k0 + kq];
            As[kq + 0][r] = va.x; As[kq + 1][r] = va.y;
            As[kq + 2][r] = va.z; As[kq + 3][r] = va.w;
        }
        // W tile 16x64
        {
            int kk = tid >> 4, cq = (tid & 15) * 4;
            float4 vb = *(const float4*)&W[(size_t)(k0 + kk) * NC + j0 + cq];
            *(float4*)&Bs[kk][cq] = vb;
        }
        __syncthreads();
#pragma unroll
        for (int kk = 0; kk < 16; kk++) {
            float4 a4 = *(float4*)&As[kk][ty * 4];
            float4 b4 = *(float4*)&Bs[kk][tx * 4];
            float av[4] = {a4.x, a4.y, a4.z, a4.w};
            float bv[4] = {b4.x, b4.y, b4.z, b4.w};
#pragma unroll
            for (int ii = 0; ii < 4; ii++)
#pragma unroll
                for (int jj = 0; jj < 4; jj++)
                    acc[ii][jj] += av[ii] * bv[jj];
        }
        __syncthreads();
    }
#pragma unroll
    for (int ii = 0; ii < 4; ii++) {
        int row = i0 + ty * 4 + ii;
        float sc = scale[row];
        float4 o = make_float4(acc[ii][0] * sc, acc[ii][1] * sc,
                               acc[ii][2] * sc, acc[ii][3] * sc);
        *(float4*)&out[(size_t)row * NC + j0 + tx * 4] = o;
    }
}

// ---------------- CSR gather-aggregate (+ norm_in, bias, optional relu) ----------------

template<int DIM, bool RELU>
__global__ void agg_kernel(const int* __restrict__ row_start, const int* __restrict__ sorted_src,
                           const float* __restrict__ msg, const float* __restrict__ norm_in,
                           const float* __restrict__ bias, float* __restrict__ out) {
    int n = blockIdx.x;
    int c = threadIdx.x;
    int e0 = row_start[n], e1 = row_start[n + 1];
    float acc = 0.f;
    for (int e = e0; e < e1; e++) {
        int s_node = sorted_src[e];
        acc += msg[(size_t)s_node * DIM + c];
    }
    float h = acc * norm_in[n] + bias[c];
    if (RELU) h = fmaxf(h, 0.f);
    out[(size_t)n * DIM + c] = h;
}

// ---------------- decoder: out[i][j] = sigmoid(dot64(z[i], z[j])) ----------------
// 64x64 tile per block, 256 threads, 4x4 microtile, K=64 fully in LDS (transposed).

__global__ __launch_bounds__(256) void decoder_kernel(const float* __restrict__ z,
                                                      float* __restrict__ out) {
    __shared__ float ZiT[64][68];  // [k][row]
    __shared__ float ZjT[64][68];  // [k][col]
    const int tx = threadIdx.x, ty = threadIdx.y;
    const int tid = ty * 16 + tx;
    const int i0 = blockIdx.y * 64;
    const int j0 = blockIdx.x * 64;

#pragma unroll
    for (int l = 0; l < 4; l++) {
        int idx4 = tid + l * 256;          // float4 index into 64x64 tile
        int r = idx4 >> 4;                 // row 0..63
        int cq = (idx4 & 15) * 4;          // col quad
        float4 vi = *(const float4*)&z[(size_t)(i0 + r) * H2 + cq];
        ZiT[cq + 0][r] = vi.x; ZiT[cq + 1][r] = vi.y;
        ZiT[cq + 2][r] = vi.z; ZiT[cq + 3][r] = vi.w;
        float4 vj = *(const float4*)&z[(size_t)(j0 + r) * H2 + cq];
        ZjT[cq + 0][r] = vj.x; ZjT[cq + 1][r] = vj.y;
        ZjT[cq + 2][r] = vj.z; ZjT[cq + 3][r] = vj.w;
    }
    __syncthreads();

    float acc[4][4] = {};
#pragma unroll 8
    for (int k = 0; k < 64; k++) {
        float4 a4 = *(float4*)&ZiT[k][ty * 4];
        float4 b4 = *(float4*)&ZjT[k][tx * 4];
        float av[4] = {a4.x, a4.y, a4.z, a4.w};
        float bv[4] = {b4.x, b4.y, b4.z, b4.w};
#pragma unroll
        for (int ii = 0; ii < 4; ii++)
#pragma unroll
            for (int jj = 0; jj < 4; jj++)
                acc[ii][jj] += av[ii] * bv[jj];
    }

#pragma unroll
    for (int ii = 0; ii < 4; ii++) {
        int row = i0 + ty * 4 + ii;
        float4 o;
        o.x = 1.f / (1.f + __expf(-acc[ii][0]));
        o.y = 1.f / (1.f + __expf(-acc[ii][1]));
        o.z = 1.f / (1.f + __expf(-acc[ii][2]));
        o.w = 1.f / (1.f + __expf(-acc[ii][3]));
        *(float4*)&out[(size_t)row * NNODES + j0 + tx * 4] = o;
    }
}

// ---------------- launcher ----------------

extern "C" void kernel_launch(void* const* d_in, const int* in_sizes, int n_in,
                              void* d_out, int out_size, void* d_ws, size_t ws_size,
                              hipStream_t stream) {
    const float* features = (const float*)d_in[0];
    const int*   src      = (const int*)d_in[1];
    const int*   dst      = (const int*)d_in[2];
    const float* W1       = (const float*)d_in[3];
    const float* b1       = (const float*)d_in[4];
    const float* W2       = (const float*)d_in[5];
    const float* b2       = (const float*)d_in[6];
    float* out = (float*)d_out;

    char* p = (char*)d_ws;
    auto alloc = [&](size_t bytes) -> void* {
        void* q = (void*)p;
        p += (bytes + 255) & ~(size_t)255;
        return q;
    };
    int*   deg_out_i  = (int*)alloc(NNODES * 4);
    int*   deg_in_i   = (int*)alloc(NNODES * 4);
    int*   cursor     = (int*)alloc(NNODES * 4);
    int*   row_start  = (int*)alloc((NNODES + 1) * 4);
    float* norm_out   = (float*)alloc(NNODES * 4);
    float* norm_in    = (float*)alloc(NNODES * 4);
    int*   sorted_src = (int*)alloc(NEDGES * 4);
    float* xw_s       = (float*)alloc((size_t)NNODES * H1 * 4);
    float* h          = (float*)alloc((size_t)NNODES * H1 * 4);
    float* hw_s       = (float*)alloc((size_t)NNODES * H2 * 4);
    float* z          = (float*)alloc((size_t)NNODES * H2 * 4);

    // deg_out_i / deg_in_i / cursor are contiguous (each 32 KiB, 256-aligned)
    hipMemsetAsync(deg_out_i, 0, 3 * NNODES * 4, stream);

    deg_kernel<<<NEDGES / 256, 256, 0, stream>>>(src, dst, deg_out_i, deg_in_i);
    norm_kernel<<<NNODES / 256, 256, 0, stream>>>(deg_out_i, deg_in_i, norm_out, norm_in);
    scan_kernel<<<1, 1024, 0, stream>>>(deg_in_i, row_start);
    bucket_kernel<<<NEDGES / 256, 256, 0, stream>>>(src, dst, row_start, cursor, sorted_src);

    // layer 1: xw_s = (X @ W1) * norm_out ; h = relu(agg * norm_in + b1)
    gemm_scale_kernel<INDIM, H1><<<dim3(128, H1 / 64), dim3(16, 16), 0, stream>>>(
        features, W1, norm_out, xw_s);
    agg_kernel<H1, true><<<NNODES, H1, 0, stream>>>(row_start, sorted_src, xw_s, norm_in, b1, h);

    // layer 2: hw_s = (h @ W2) * norm_out ; z = agg * norm_in + b2
    gemm_scale_kernel<H1, H2><<<dim3(128, 1), dim3(16, 16), 0, stream>>>(
        h, W2, norm_out, hw_s);
    agg_kernel<H2, false><<<NNODES, H2, 0, stream>>>(row_start, sorted_src, hw_s, norm_in, b2, z);

    // decoder
    decoder_kernel<<<dim3(NNODES / 64, NNODES / 64), dim3(16, 16), 0, stream>>>(z, out);
}

// Round 2
// 201.898 us; speedup vs baseline: 1.5354x; 1.5354x over previous
//
#include <hip/hip_runtime.h>
#include <hip/hip_bf16.h>
#include <math.h>

#define NNODES 8192
#define NEDGES 262144
#define INDIM  512
#define H1     256
#define H2     64

typedef __attribute__((ext_vector_type(8))) short bf16x8;  // 8 bf16 = 4 VGPRs
typedef __attribute__((ext_vector_type(4))) float f32x4;   // MFMA C/D frag

// ---------------- degree / norm / CSR build ----------------

__global__ void deg_kernel(const int* __restrict__ src, const int* __restrict__ dst,
                           int* deg_out, int* deg_in) {
    int e = blockIdx.x * blockDim.x + threadIdx.x;
    if (e < NEDGES) {
        atomicAdd(&deg_out[src[e]], 1);
        atomicAdd(&deg_in[dst[e]], 1);
    }
}

__global__ void norm_kernel(const int* __restrict__ deg_out, const int* __restrict__ deg_in,
                            float* norm_out, float* norm_in) {
    int i = blockIdx.x * blockDim.x + threadIdx.x;
    if (i < NNODES) {
        norm_out[i] = 1.0f / sqrtf(fmaxf((float)deg_out[i], 1.0f));
        norm_in[i]  = 1.0f / sqrtf(fmaxf((float)deg_in[i],  1.0f));
    }
}

// exclusive prefix sum of deg_in over 8192 nodes, single block of 1024 threads
__global__ __launch_bounds__(1024) void scan_kernel(const int* __restrict__ deg_in,
                                                    int* __restrict__ row_start) {
    __shared__ int part[1024];
    int t = threadIdx.x;
    int v[8]; int s = 0;
#pragma unroll
    for (int u = 0; u < 8; u++) { v[u] = deg_in[t * 8 + u]; s += v[u]; }
    part[t] = s; __syncthreads();
    for (int off = 1; off < 1024; off <<= 1) {
        int x = part[t];
        if (t >= off) x += part[t - off];
        __syncthreads();
        part[t] = x;
        __syncthreads();
    }
    int run = part[t] - s;   // exclusive prefix of this thread's chunk
#pragma unroll
    for (int u = 0; u < 8; u++) { row_start[t * 8 + u] = run; run += v[u]; }
    if (t == 1023) row_start[NNODES] = run;
}

__global__ void bucket_kernel(const int* __restrict__ src, const int* __restrict__ dst,
                              const int* __restrict__ row_start,
                              int* cursor, int* __restrict__ sorted_src) {
    int e = blockIdx.x * blockDim.x + threadIdx.x;
    if (e < NEDGES) {
        int d = dst[e];
        int p = atomicAdd(&cursor[d], 1);
        sorted_src[row_start[d] + p] = src[e];
    }
}

// ---------------- fp32 tiled GEMM: out[i][c] = (X@W)[i][c] * scale[i] ----------------

template<int K, int NC>
__global__ __launch_bounds__(256) void gemm_scale_kernel(const float* __restrict__ X,
                                                         const float* __restrict__ W,
                                                         const float* __restrict__ scale,
                                                         float* __restrict__ out) {
    __shared__ float As[16][68];
    __shared__ float Bs[16][68];
    const int tx = threadIdx.x, ty = threadIdx.y;
    const int tid = ty * 16 + tx;
    const int i0 = blockIdx.x * 64;
    const int j0 = blockIdx.y * 64;
    float acc[4][4] = {};

    for (int k0 = 0; k0 < K; k0 += 16) {
        {
            int r = tid >> 2, kq = (tid & 3) * 4;
            float4 va = *(const float4*)&X[(size_t)(i0 + r) * K + k0 + kq];
            As[kq + 0][r] = va.x; As[kq + 1][r] = va.y;
            As[kq + 2][r] = va.z; As[kq + 3][r] = va.w;
        }
        {
            int kk = tid >> 4, cq = (tid & 15) * 4;
            float4 vb = *(const float4*)&W[(size_t)(k0 + kk) * NC + j0 + cq];
            *(float4*)&Bs[kk][cq] = vb;
        }
        __syncthreads();
#pragma unroll
        for (int kk = 0; kk < 16; kk++) {
            float4 a4 = *(float4*)&As[kk][ty * 4];
            float4 b4 = *(float4*)&Bs[kk][tx * 4];
            float av[4] = {a4.x, a4.y, a4.z, a4.w};
            float bv[4] = {b4.x, b4.y, b4.z, b4.w};
#pragma unroll
            for (int ii = 0; ii < 4; ii++)
#pragma unroll
                for (int jj = 0; jj < 4; jj++)
                    acc[ii][jj] += av[ii] * bv[jj];
        }
        __syncthreads();
    }
#pragma unroll
    for (int ii = 0; ii < 4; ii++) {
        int row = i0 + ty * 4 + ii;
        float sc = scale[row];
        float4 o = make_float4(acc[ii][0] * sc, acc[ii][1] * sc,
                               acc[ii][2] * sc, acc[ii][3] * sc);
        *(float4*)&out[(size_t)row * NC + j0 + tx * 4] = o;
    }
}

// ---------------- CSR gather-aggregate ----------------
// H1=256: one wave per node, float4 per lane (64 lanes x 4 cols = 256).

__global__ void agg256_kernel(const int* __restrict__ row_start, const int* __restrict__ sorted_src,
                              const float* __restrict__ msg, const float* __restrict__ norm_in,
                              const float* __restrict__ bias, float* __restrict__ out) {
    int n = blockIdx.x;
    int c4 = threadIdx.x * 4;
    int e0 = row_start[n], e1 = row_start[n + 1];
    float4 acc = make_float4(0.f, 0.f, 0.f, 0.f);
    for (int e = e0; e < e1; e++) {
        int s_node = sorted_src[e];
        float4 v = *(const float4*)&msg[(size_t)s_node * H1 + c4];
        acc.x += v.x; acc.y += v.y; acc.z += v.z; acc.w += v.w;
    }
    float ni = norm_in[n];
    float4 bb = *(const float4*)&bias[c4];
    float4 h = make_float4(fmaxf(acc.x * ni + bb.x, 0.f),
                           fmaxf(acc.y * ni + bb.y, 0.f),
                           fmaxf(acc.z * ni + bb.z, 0.f),
                           fmaxf(acc.w * ni + bb.w, 0.f));
    *(float4*)&out[(size_t)n * H1 + c4] = h;
}

// H2=64: one wave per node, 1 col per lane; emits bf16 z directly.

__global__ void agg64_bf16_kernel(const int* __restrict__ row_start, const int* __restrict__ sorted_src,
                                  const float* __restrict__ msg, const float* __restrict__ norm_in,
                                  const float* __restrict__ bias, __hip_bfloat16* __restrict__ out) {
    int n = blockIdx.x;
    int c = threadIdx.x;
    int e0 = row_start[n], e1 = row_start[n + 1];
    float acc = 0.f;
    for (int e = e0; e < e1; e++) {
        int s_node = sorted_src[e];
        acc += msg[(size_t)s_node * H2 + c];
    }
    float h = acc * norm_in[n] + bias[c];
    out[(size_t)n * H2 + c] = __float2bfloat16(h);
}

// ---------------- decoder: out = sigmoid(Zb @ Zb^T) via bf16 MFMA ----------------
// Block = 256 threads = 4 waves. Block tile 128x128; wave tile 32x128.
// Fragments load straight from global (zb is 1 MB, L2-resident). No LDS.

__global__ __launch_bounds__(256) void decoder_mfma_kernel(const __hip_bfloat16* __restrict__ zbf,
                                                           float* __restrict__ out) {
    const short* zb = (const short*)zbf;
    const int lane = threadIdx.x & 63;
    const int wid  = threadIdx.x >> 6;
    const int i0 = blockIdx.y * 128 + wid * 32;
    const int j0 = blockIdx.x * 128;
    const int fr = lane & 15;     // A-row / B-col within 16-tile
    const int kg = lane >> 4;     // k-group: elements kg*8 .. kg*8+7

    f32x4 acc[2][8] = {};
#pragma unroll
    for (int ks = 0; ks < 2; ks++) {        // K = 64 = 2 x 32
        bf16x8 a[2], b[8];
#pragma unroll
        for (int m = 0; m < 2; m++)
            a[m] = *(const bf16x8*)&zb[(size_t)(i0 + m * 16 + fr) * H2 + ks * 32 + kg * 8];
#pragma unroll
        for (int n = 0; n < 8; n++)
            b[n] = *(const bf16x8*)&zb[(size_t)(j0 + n * 16 + fr) * H2 + ks * 32 + kg * 8];
#pragma unroll
        for (int m = 0; m < 2; m++)
#pragma unroll
            for (int n = 0; n < 8; n++)
                acc[m][n] = __builtin_amdgcn_mfma_f32_16x16x32_bf16(a[m], b[n], acc[m][n], 0, 0, 0);
    }

    // C/D layout: col = lane&15, row = (lane>>4)*4 + reg   [verified m89/m91]
    const int col = lane & 15;
    const int rg4 = (lane >> 4) * 4;
#pragma unroll
    for (int m = 0; m < 2; m++)
#pragma unroll
        for (int n = 0; n < 8; n++) {
            size_t base = (size_t)(i0 + m * 16 + rg4) * NNODES + j0 + n * 16 + col;
#pragma unroll
            for (int r = 0; r < 4; r++)
                out[base + (size_t)r * NNODES] = 1.f / (1.f + __expf(-acc[m][n][r]));
        }
}

// ---------------- launcher ----------------

extern "C" void kernel_launch(void* const* d_in, const int* in_sizes, int n_in,
                              void* d_out, int out_size, void* d_ws, size_t ws_size,
                              hipStream_t stream) {
    const float* features = (const float*)d_in[0];
    const int*   src      = (const int*)d_in[1];
    const int*   dst      = (const int*)d_in[2];
    const float* W1       = (const float*)d_in[3];
    const float* b1       = (const float*)d_in[4];
    const float* W2       = (const float*)d_in[5];
    const float* b2       = (const float*)d_in[6];
    float* out = (float*)d_out;

    char* p = (char*)d_ws;
    auto alloc = [&](size_t bytes) -> void* {
        void* q = (void*)p;
        p += (bytes + 255) & ~(size_t)255;
        return q;
    };
    int*   deg_out_i  = (int*)alloc(NNODES * 4);
    int*   deg_in_i   = (int*)alloc(NNODES * 4);
    int*   cursor     = (int*)alloc(NNODES * 4);
    int*   row_start  = (int*)alloc((NNODES + 1) * 4);
    float* norm_out   = (float*)alloc(NNODES * 4);
    float* norm_in    = (float*)alloc(NNODES * 4);
    int*   sorted_src = (int*)alloc(NEDGES * 4);
    float* xw_s       = (float*)alloc((size_t)NNODES * H1 * 4);
    float* h          = (float*)alloc((size_t)NNODES * H1 * 4);
    float* hw_s       = (float*)alloc((size_t)NNODES * H2 * 4);
    __hip_bfloat16* zb = (__hip_bfloat16*)alloc((size_t)NNODES * H2 * 2);

    // deg_out_i / deg_in_i / cursor are contiguous (each 32 KiB, 256-aligned)
    hipMemsetAsync(deg_out_i, 0, 3 * NNODES * 4, stream);

    deg_kernel<<<NEDGES / 256, 256, 0, stream>>>(src, dst, deg_out_i, deg_in_i);
    norm_kernel<<<NNODES / 256, 256, 0, stream>>>(deg_out_i, deg_in_i, norm_out, norm_in);
    scan_kernel<<<1, 1024, 0, stream>>>(deg_in_i, row_start);
    bucket_kernel<<<NEDGES / 256, 256, 0, stream>>>(src, dst, row_start, cursor, sorted_src);

    // layer 1: xw_s = (X @ W1) * norm_out ; h = relu(agg * norm_in + b1)
    gemm_scale_kernel<INDIM, H1><<<dim3(128, H1 / 64), dim3(16, 16), 0, stream>>>(
        features, W1, norm_out, xw_s);
    agg256_kernel<<<NNODES, 64, 0, stream>>>(row_start, sorted_src, xw_s, norm_in, b1, h);

    // layer 2: hw_s = (h @ W2) * norm_out ; z = agg * norm_in + b2  (bf16 out)
    gemm_scale_kernel<H1, H2><<<dim3(128, 1), dim3(16, 16), 0, stream>>>(
        h, W2, norm_out, hw_s);
    agg64_bf16_kernel<<<NNODES, 64, 0, stream>>>(row_start, sorted_src, hw_s, norm_in, b2, zb);

    // decoder: sigmoid(zb @ zb^T)
    decoder_mfma_kernel<<<dim3(NNODES / 128, NNODES / 128), dim3(256), 0, stream>>>(zb, out);
}

// Round 3
// 178.719 us; speedup vs baseline: 1.7345x; 1.1297x over previous
//
#include <hip/hip_runtime.h>
#include <hip/hip_bf16.h>
#include <math.h>

#define NNODES 8192
#define NEDGES 262144
#define INDIM  512
#define H1     256
#define H2     64

typedef __attribute__((ext_vector_type(8))) short bf16x8;  // 8 bf16 = 4 VGPRs
typedef __attribute__((ext_vector_type(4))) float f32x4;   // MFMA C/D frag

static __device__ __forceinline__ float bf2f(unsigned short u) {
    return __uint_as_float((unsigned)u << 16);
}
static __device__ __forceinline__ unsigned short f2bf(float f) {
    __hip_bfloat16 h = __float2bfloat16(f);
    return *(unsigned short*)&h;
}

// ---------------- degree / norm / CSR build ----------------

__global__ void deg_kernel(const int* __restrict__ src, const int* __restrict__ dst,
                           int* deg_out, int* deg_in) {
    int e = blockIdx.x * blockDim.x + threadIdx.x;
    if (e < NEDGES) {
        atomicAdd(&deg_out[src[e]], 1);
        atomicAdd(&deg_in[dst[e]], 1);
    }
}

__global__ void norm_kernel(const int* __restrict__ deg_out, const int* __restrict__ deg_in,
                            float* norm_out, float* norm_in) {
    int i = blockIdx.x * blockDim.x + threadIdx.x;
    if (i < NNODES) {
        norm_out[i] = 1.0f / sqrtf(fmaxf((float)deg_out[i], 1.0f));
        norm_in[i]  = 1.0f / sqrtf(fmaxf((float)deg_in[i],  1.0f));
    }
}

// exclusive prefix sum of deg_in over 8192 nodes, single block of 1024 threads
__global__ __launch_bounds__(1024) void scan_kernel(const int* __restrict__ deg_in,
                                                    int* __restrict__ row_start) {
    __shared__ int part[1024];
    int t = threadIdx.x;
    int v[8]; int s = 0;
#pragma unroll
    for (int u = 0; u < 8; u++) { v[u] = deg_in[t * 8 + u]; s += v[u]; }
    part[t] = s; __syncthreads();
    for (int off = 1; off < 1024; off <<= 1) {
        int x = part[t];
        if (t >= off) x += part[t - off];
        __syncthreads();
        part[t] = x;
        __syncthreads();
    }
    int run = part[t] - s;
#pragma unroll
    for (int u = 0; u < 8; u++) { row_start[t * 8 + u] = run; run += v[u]; }
    if (t == 1023) row_start[NNODES] = run;
}

__global__ void bucket_kernel(const int* __restrict__ src, const int* __restrict__ dst,
                              const int* __restrict__ row_start,
                              int* cursor, int* __restrict__ sorted_src) {
    int e = blockIdx.x * blockDim.x + threadIdx.x;
    if (e < NEDGES) {
        int d = dst[e];
        int p = atomicAdd(&cursor[d], 1);
        sorted_src[row_start[d] + p] = src[e];
    }
}

// ---------------- casts / transposes ----------------

// fp32 -> bf16, 4 elements per thread
__global__ void cast4_kernel(const float* __restrict__ in, __hip_bfloat16* __restrict__ out) {
    int t = blockIdx.x * blockDim.x + threadIdx.x;
    float4 v = ((const float4*)in)[t];
    ushort4 o;
    o.x = f2bf(v.x); o.y = f2bf(v.y); o.z = f2bf(v.z); o.w = f2bf(v.w);
    ((ushort4*)out)[t] = o;
}

// W[K][N] fp32 -> WT[N][K] bf16 (coalesced reads, scattered 2B writes; tiny)
template<int K, int N>
__global__ void wtrans_kernel(const float* __restrict__ W, __hip_bfloat16* __restrict__ WT) {
    int t = blockIdx.x * blockDim.x + threadIdx.x;
    if (t < K * N) {
        int k = t / N, c = t % N;
        WT[(size_t)c * K + k] = __float2bfloat16(W[t]);
    }
}

// ---------------- bf16 MFMA GEMM: out[i][j] = (A @ BT^T)[i][j] * scale[i] (bf16 out) ----
// A: [M][K] bf16 row-major; BT: [N][K] bf16 row-major (i.e. W^T rows = W columns).
// Block = 256 threads = 4 waves. Block tile MT x NT; wave tile (MT/4) x NT.
// Fragments straight from global (operands L2-resident, no LDS).

template<int K, int MT, int NT, int NOUT>
__global__ __launch_bounds__(256) void gemm_mfma_kernel(const __hip_bfloat16* __restrict__ Af,
                                                        const __hip_bfloat16* __restrict__ BTf,
                                                        const float* __restrict__ scale,
                                                        __hip_bfloat16* __restrict__ outf) {
    constexpr int AM = MT / 64;   // A-frags per wave (16-row tiles)
    constexpr int BN = NT / 16;   // B-frags
    const short* A  = (const short*)Af;
    const short* BT = (const short*)BTf;
    short* out = (short*)outf;
    const int lane = threadIdx.x & 63;
    const int wid  = threadIdx.x >> 6;
    const int i0 = blockIdx.y * MT + wid * (MT / 4);
    const int j0 = blockIdx.x * NT;
    const int fr = lane & 15;
    const int kg = lane >> 4;

    f32x4 acc[AM][BN] = {};
    for (int k0 = 0; k0 < K; k0 += 32) {
        bf16x8 a[AM], b[BN];
#pragma unroll
        for (int m = 0; m < AM; m++)
            a[m] = *(const bf16x8*)&A[(size_t)(i0 + m * 16 + fr) * K + k0 + kg * 8];
#pragma unroll
        for (int n = 0; n < BN; n++)
            b[n] = *(const bf16x8*)&BT[(size_t)(j0 + n * 16 + fr) * K + k0 + kg * 8];
#pragma unroll
        for (int m = 0; m < AM; m++)
#pragma unroll
            for (int n = 0; n < BN; n++)
                acc[m][n] = __builtin_amdgcn_mfma_f32_16x16x32_bf16(a[m], b[n], acc[m][n], 0, 0, 0);
    }

    const int col = lane & 15;
    const int rg4 = (lane >> 4) * 4;
#pragma unroll
    for (int m = 0; m < AM; m++)
#pragma unroll
        for (int r = 0; r < 4; r++) {
            int row = i0 + m * 16 + rg4 + r;
            float sc = scale[row];
#pragma unroll
            for (int n = 0; n < BN; n++)
                out[(size_t)row * NOUT + j0 + n * 16 + col] = f2bf(acc[m][n][r] * sc);
        }
}

// ---------------- CSR gather-aggregate (bf16 messages) ----------------
// H1=256: one wave per node, 4 bf16 cols per lane; fp32 accum; bf16 out (relu).

__global__ void agg256_kernel(const int* __restrict__ row_start, const int* __restrict__ sorted_src,
                              const __hip_bfloat16* __restrict__ msgb, const float* __restrict__ norm_in,
                              const float* __restrict__ bias, __hip_bfloat16* __restrict__ outb) {
    const ushort4* msg = (const ushort4*)msgb;   // 64 x ushort4 per row
    int n = blockIdx.x;
    int lane = threadIdx.x;
    int e0 = row_start[n], e1 = row_start[n + 1];
    float ax = 0.f, ay = 0.f, az = 0.f, aw = 0.f;
    int e = e0;
    for (; e + 1 < e1; e += 2) {
        int s0 = sorted_src[e], s1 = sorted_src[e + 1];
        ushort4 v0 = msg[(size_t)s0 * 64 + lane];
        ushort4 v1 = msg[(size_t)s1 * 64 + lane];
        ax += bf2f(v0.x) + bf2f(v1.x);
        ay += bf2f(v0.y) + bf2f(v1.y);
        az += bf2f(v0.z) + bf2f(v1.z);
        aw += bf2f(v0.w) + bf2f(v1.w);
    }
    if (e < e1) {
        ushort4 v0 = msg[(size_t)sorted_src[e] * 64 + lane];
        ax += bf2f(v0.x); ay += bf2f(v0.y); az += bf2f(v0.z); aw += bf2f(v0.w);
    }
    float ni = norm_in[n];
    float4 bb = ((const float4*)bias)[lane];
    ushort4 o;
    o.x = f2bf(fmaxf(ax * ni + bb.x, 0.f));
    o.y = f2bf(fmaxf(ay * ni + bb.y, 0.f));
    o.z = f2bf(fmaxf(az * ni + bb.z, 0.f));
    o.w = f2bf(fmaxf(aw * ni + bb.w, 0.f));
    ((ushort4*)outb)[(size_t)n * 64 + lane] = o;
}

// H2=64: one wave per node, 2 edges in flight (lane halves), 2 bf16 cols per lane.

__global__ void agg64_kernel(const int* __restrict__ row_start, const int* __restrict__ sorted_src,
                             const __hip_bfloat16* __restrict__ msgb, const float* __restrict__ norm_in,
                             const float* __restrict__ bias, __hip_bfloat16* __restrict__ outb) {
    const unsigned* msg = (const unsigned*)msgb;   // 32 x (2 bf16) per row
    int n = blockIdx.x;
    int lane = threadIdx.x;
    int half = lane >> 5, li = lane & 31;
    int e0 = row_start[n], e1 = row_start[n + 1];
    float ax = 0.f, ay = 0.f;
    for (int e = e0 + half; e < e1; e += 2) {
        unsigned u = msg[(size_t)sorted_src[e] * 32 + li];
        ax += bf2f((unsigned short)(u & 0xffff));
        ay += bf2f((unsigned short)(u >> 16));
    }
    ax += __shfl_xor(ax, 32);
    ay += __shfl_xor(ay, 32);
    if (half == 0) {
        float ni = norm_in[n];
        float z0 = ax * ni + bias[2 * li];
        float z1 = ay * ni + bias[2 * li + 1];
        unsigned o = (unsigned)f2bf(z0) | ((unsigned)f2bf(z1) << 16);
        ((unsigned*)outb)[(size_t)n * 32 + li] = o;
    }
}

// ---------------- decoder: out = sigmoid(Zb @ Zb^T) via bf16 MFMA ----------------

__global__ __launch_bounds__(256) void decoder_mfma_kernel(const __hip_bfloat16* __restrict__ zbf,
                                                           float* __restrict__ out) {
    const short* zb = (const short*)zbf;
    const int lane = threadIdx.x & 63;
    const int wid  = threadIdx.x >> 6;
    const int i0 = blockIdx.y * 128 + wid * 32;
    const int j0 = blockIdx.x * 128;
    const int fr = lane & 15;
    const int kg = lane >> 4;

    f32x4 acc[2][8] = {};
#pragma unroll
    for (int ks = 0; ks < 2; ks++) {
        bf16x8 a[2], b[8];
#pragma unroll
        for (int m = 0; m < 2; m++)
            a[m] = *(const bf16x8*)&zb[(size_t)(i0 + m * 16 + fr) * H2 + ks * 32 + kg * 8];
#pragma unroll
        for (int n = 0; n < 8; n++)
            b[n] = *(const bf16x8*)&zb[(size_t)(j0 + n * 16 + fr) * H2 + ks * 32 + kg * 8];
#pragma unroll
        for (int m = 0; m < 2; m++)
#pragma unroll
            for (int n = 0; n < 8; n++)
                acc[m][n] = __builtin_amdgcn_mfma_f32_16x16x32_bf16(a[m], b[n], acc[m][n], 0, 0, 0);
    }

    const int col = lane & 15;
    const int rg4 = (lane >> 4) * 4;
#pragma unroll
    for (int m = 0; m < 2; m++)
#pragma unroll
        for (int n = 0; n < 8; n++) {
            size_t base = (size_t)(i0 + m * 16 + rg4) * NNODES + j0 + n * 16 + col;
#pragma unroll
            for (int r = 0; r < 4; r++) {
                float v = 1.f / (1.f + __expf(-acc[m][n][r]));
                __builtin_nontemporal_store(v, &out[base + (size_t)r * NNODES]);
            }
        }
}

// ---------------- launcher ----------------

extern "C" void kernel_launch(void* const* d_in, const int* in_sizes, int n_in,
                              void* d_out, int out_size, void* d_ws, size_t ws_size,
                              hipStream_t stream) {
    const float* features = (const float*)d_in[0];
    const int*   src      = (const int*)d_in[1];
    const int*   dst      = (const int*)d_in[2];
    const float* W1       = (const float*)d_in[3];
    const float* b1       = (const float*)d_in[4];
    const float* W2       = (const float*)d_in[5];
    const float* b2       = (const float*)d_in[6];
    float* out = (float*)d_out;

    char* p = (char*)d_ws;
    auto alloc = [&](size_t bytes) -> void* {
        void* q = (void*)p;
        p += (bytes + 255) & ~(size_t)255;
        return q;
    };
    int*   deg_out_i  = (int*)alloc(NNODES * 4);
    int*   deg_in_i   = (int*)alloc(NNODES * 4);
    int*   cursor     = (int*)alloc(NNODES * 4);
    int*   row_start  = (int*)alloc((NNODES + 1) * 4);
    float* norm_out   = (float*)alloc(NNODES * 4);
    float* norm_in    = (float*)alloc(NNODES * 4);
    int*   sorted_src = (int*)alloc(NEDGES * 4);
    __hip_bfloat16* featb = (__hip_bfloat16*)alloc((size_t)NNODES * INDIM * 2);
    __hip_bfloat16* w1t   = (__hip_bfloat16*)alloc((size_t)H1 * INDIM * 2);
    __hip_bfloat16* w2t   = (__hip_bfloat16*)alloc((size_t)H2 * H1 * 2);
    __hip_bfloat16* xwb   = (__hip_bfloat16*)alloc((size_t)NNODES * H1 * 2);
    __hip_bfloat16* hb    = (__hip_bfloat16*)alloc((size_t)NNODES * H1 * 2);
    __hip_bfloat16* hwb   = (__hip_bfloat16*)alloc((size_t)NNODES * H2 * 2);
    __hip_bfloat16* zb    = (__hip_bfloat16*)alloc((size_t)NNODES * H2 * 2);

    // deg_out_i / deg_in_i / cursor are contiguous (each 32 KiB, 256-aligned)
    hipMemsetAsync(deg_out_i, 0, 3 * NNODES * 4, stream);

    deg_kernel<<<NEDGES / 256, 256, 0, stream>>>(src, dst, deg_out_i, deg_in_i);
    norm_kernel<<<NNODES / 256, 256, 0, stream>>>(deg_out_i, deg_in_i, norm_out, norm_in);
    scan_kernel<<<1, 1024, 0, stream>>>(deg_in_i, row_start);
    bucket_kernel<<<NEDGES / 256, 256, 0, stream>>>(src, dst, row_start, cursor, sorted_src);

    // casts / transposes
    cast4_kernel<<<NNODES * INDIM / 4 / 256, 256, 0, stream>>>(features, featb);
    wtrans_kernel<INDIM, H1><<<(INDIM * H1 + 255) / 256, 256, 0, stream>>>(W1, w1t);
    wtrans_kernel<H1, H2><<<(H1 * H2 + 255) / 256, 256, 0, stream>>>(W2, w2t);

    // layer 1: xwb = bf16((X @ W1) * norm_out) ; hb = bf16(relu(agg * norm_in + b1))
    gemm_mfma_kernel<INDIM, 128, 128, H1><<<dim3(H1 / 128, NNODES / 128), 256, 0, stream>>>(
        featb, w1t, norm_out, xwb);
    agg256_kernel<<<NNODES, 64, 0, stream>>>(row_start, sorted_src, xwb, norm_in, b1, hb);

    // layer 2: hwb = bf16((h @ W2) * norm_out) ; zb = bf16(agg * norm_in + b2)
    gemm_mfma_kernel<H1, 64, 64, H2><<<dim3(1, NNODES / 64), 256, 0, stream>>>(
        hb, w2t, norm_out, hwb);
    agg64_kernel<<<NNODES, 64, 0, stream>>>(row_start, sorted_src, hwb, norm_in, b2, zb);

    // decoder: sigmoid(zb @ zb^T)
    decoder_mfma_kernel<<<dim3(NNODES / 128, NNODES / 128), 256, 0, stream>>>(zb, out);
}